// Round 5
// baseline (234.299 us; speedup 1.0000x reference)
//
#include <hip/hip_runtime.h>

// LIF spike scan: x[N, T=32] fp32, scan over contiguous T axis.
//   u = 0.25*u*(1-o_prev) + x_t ;  o = (u > 0.5) ? 1 : 0
// 0.25*u exact (pow2), (1-o) in {0,1} exact -> bit-exact vs numpy fp32 ref.
//
// R7 = R6 (zero-LDS, 4-lane/neuron register scan) + TRUE streaming stores.
//  - R0/R5/R6 post-mortem: four structures, identical 80-83us @2.5TB/s HBM,
//    while the harness memset blit does 6.65TB/s. Supply-side limiter.
//  - FETCH_SIZE=65.6MB = 49% of input every round: write-allocated output
//    (134MB) + input (134MB) thrash the 256MB L3 -> input half-evicted.
//    __builtin_nontemporal_store changed FETCH by 0 -> its nt hint does not
//    prevent allocation.
//  - Fix: inline-asm global_store_dwordx4 with the full gfx950 streaming
//    cache policy `sc0 sc1 nt` (post-gfx940 spelling; glc/slc invalid).
//    If output bypasses allocation: input becomes ~fully L3-resident
//    across iterations (FETCH -> ~0) and writes take the memset's path.
//  - Everything else is byte-identical to R6 for a clean A/B.

constexpr float TAU = 0.25f;
constexpr float VTH = 0.5f;
constexpr int BLOCK = 256;
constexpr int GRID = 2048;          // 8 blocks/CU, grid-stride over chunks

typedef float f32x4 __attribute__((ext_vector_type(4)));

__device__ __forceinline__ void store_stream(f32x4* p, f32x4 v) {
    // Streaming store: bypass cache allocation (sc0 sc1) + non-temporal (nt).
    asm volatile("global_store_dwordx4 %0, %1, off sc0 sc1 nt"
                 :: "v"(p), "v"(v) : "memory");
}

// One chunk = 16 neurons x 32 T = 512 floats = 128 f4 = 2 KB, one wave-iter.

__global__ __launch_bounds__(BLOCK) void LIFSpike_kernel(
    const float* __restrict__ x, float* __restrict__ out, int n_chunks) {
    const int t = threadIdx.x;
    const int lane = t & 63;
    const int j = lane & 3;                      // position within neuron group
    const int g = lane >> 2;                     // neuron group 0..15
    const int wave = blockIdx.x * (BLOCK / 64) + (t >> 6);
    const int nwaves = gridDim.x * (BLOCK / 64);

    const f32x4* __restrict__ xp = reinterpret_cast<const f32x4*>(x);
    f32x4* __restrict__ op = reinterpret_cast<f32x4*>(out);

    for (size_t c = wave; c < (size_t)n_chunks; c += nwaves) {
        // lane's two f4 slots of neuron row (c*16 + g):
        //   r0 -> timesteps 4j..4j+3, r1 -> timesteps 16+4j..16+4j+3
        const size_t a0 = c * 128 + (size_t)g * 8 + j;
        const f32x4 v0 = xp[a0];
        const f32x4 v1 = xp[a0 + 4];
        f32x4 r0, r1;

        float u = 0.0f, o = 0.0f;
#pragma unroll
        for (int s = 0; s < 8; ++s) {
            if (j == (s & 3)) {                  // owner of this 4-step segment
                const f32x4 v = (s < 4) ? v0 : v1;
                float uu = u, oo = o;
                f32x4 r;
                uu = TAU * uu * (1.0f - oo) + v.x;
                oo = (uu > VTH) ? 1.0f : 0.0f;  r.x = oo;
                uu = TAU * uu * (1.0f - oo) + v.y;
                oo = (uu > VTH) ? 1.0f : 0.0f;  r.y = oo;
                uu = TAU * uu * (1.0f - oo) + v.z;
                oo = (uu > VTH) ? 1.0f : 0.0f;  r.z = oo;
                uu = TAU * uu * (1.0f - oo) + v.w;
                oo = (uu > VTH) ? 1.0f : 0.0f;  r.w = oo;
                u = uu;
                if (s < 4) r0 = r; else r1 = r;
            }
            // Broadcast the owner's u to the whole 4-lane group; recompute o.
            u = __shfl(u, (lane & ~3) | (s & 3));
            o = (u > VTH) ? 1.0f : 0.0f;
        }

        store_stream(op + a0, r0);
        store_stream(op + a0 + 4, r1);
    }
}

extern "C" void kernel_launch(void* const* d_in, const int* in_sizes, int n_in,
                              void* d_out, int out_size, void* d_ws, size_t ws_size,
                              hipStream_t stream) {
    const float* x = (const float*)d_in[0];
    float* out = (float*)d_out;
    int n_chunks = in_sizes[0] / 512;   // 33,554,432 floats -> 65,536 chunks
    LIFSpike_kernel<<<GRID, BLOCK, 0, stream>>>(x, out, n_chunks);
}